// Round 10
// baseline (844.483 us; speedup 1.0000x reference)
//
#include <hip/hip_runtime.h>
#include <stdint.h>

typedef __attribute__((ext_vector_type(4))) float f32x4;
typedef __attribute__((ext_vector_type(8))) float f32x8;
typedef __attribute__((ext_vector_type(16))) float f32x16;
typedef __attribute__((ext_vector_type(8))) short bf16x8;
typedef __attribute__((ext_vector_type(4))) int i32x4;
typedef __attribute__((ext_vector_type(2))) int i32x2;

#define DEVI static __device__ __forceinline__

constexpr int CB  = 4;     // batch
constexpr int CS  = 2048;  // seq
constexpr int CH  = 16;    // heads
constexpr int CDH = 64;    // head dim
constexpr int CE  = 1024;  // embed

DEVI short f2bf(float x) {  // RNE float->bf16 (epilogue use)
  unsigned u = __float_as_uint(x);
  u += 0x7fffu + ((u >> 16) & 1u);
  return (short)(u >> 16);
}

DEVI int cvtpk(float lo, float hi) {  // packed f32x2 -> bf16x2 (RNE, 1 inst)
  int r;
  asm("v_cvt_pk_bf16_f32 %0, %1, %2" : "=v"(r) : "v"(lo), "v"(hi));
  return r;
}

DEVI float exp2v(float x) {  // raw v_exp_f32 (2^x)
  float r;
  asm("v_exp_f32 %0, %1" : "=v"(r) : "v"(x));
  return r;
}

DEVI float rcpv(float x) {  // v_rcp_f32 (~1 ulp)
  float r;
  asm("v_rcp_f32 %0, %1" : "=v"(r) : "v"(x));
  return r;
}

DEVI void gload16(const void* g, void* l) {
  __builtin_amdgcn_global_load_lds(
      (const __attribute__((address_space(1))) void*)g,
      (__attribute__((address_space(3))) void*)l, 16, 0, 0);
}

DEVI f32x4 mfma16(bf16x8 a, bf16x8 b, f32x4 c) {
  return __builtin_amdgcn_mfma_f32_16x16x32_bf16(a, b, c, 0, 0, 0);
}
DEVI f32x16 mfma32(bf16x8 a, bf16x8 b, f32x16 c) {
  return __builtin_amdgcn_mfma_f32_32x32x16_bf16(a, b, c, 0, 0, 0);
}

DEVI void wait_vm4_lgkm0() {
  asm volatile("s_waitcnt vmcnt(4) lgkmcnt(0)" ::: "memory");
}
DEVI void wait_vm2_lgkm0() {
  asm volatile("s_waitcnt vmcnt(2) lgkmcnt(0)" ::: "memory");
}
DEVI void wait_vm0_lgkm0() {
  asm volatile("s_waitcnt vmcnt(0) lgkmcnt(0)" ::: "memory");
}

// ---------------- W fp32 -> bf16 (once; reused by 3 projections) ------------

__global__ __launch_bounds__(256) void cvtW3(
    const float* __restrict__ w0, const float* __restrict__ w1,
    const float* __restrict__ w2, short* __restrict__ o0,
    short* __restrict__ o1, short* __restrict__ o2) {
  const float* in = blockIdx.y == 0 ? w0 : (blockIdx.y == 1 ? w1 : w2);
  short* out = blockIdx.y == 0 ? o0 : (blockIdx.y == 1 ? o1 : o2);
  size_t o = ((size_t)blockIdx.x * 256 + threadIdx.x) * 8;
  f32x4 a = *(const f32x4*)&in[o];
  f32x4 b = *(const f32x4*)&in[o + 4];
  i32x4 p = {cvtpk(a[0], a[1]), cvtpk(a[2], a[3]),
             cvtpk(b[0], b[1]), cvtpk(b[2], b[3])};
  *(i32x4*)&out[o] = p;
}

// ---------------- Pipelined GEMM: C = A * W^T + bias (round 8, kept) --------
template<int MODE, bool CVTA>
__global__ __launch_bounds__(256) void gemm2(
    const short* __restrict__ Gp, const float* __restrict__ Fp,
    const float* __restrict__ bias, void* __restrict__ outp, float scale) {
  constexpr int K = CE;
  __shared__ short Gs[6][128 * 32];  // 48KB
  __shared__ short Cs[4][128 * 32];  // 32KB
  const int t  = threadIdx.x;
  const int l  = t & 63;
  const int w  = t >> 6;
  const int g  = l >> 4;
  const int ln = l & 15;
  const int lin = blockIdx.x;
  const int wg = (lin & 7) * 64 + (lin >> 3);
  const int n0 = (wg & 7) * 128;
  const int m0 = (wg >> 3) * 128;
  const int wr = (w >> 1) * 64;
  const int wc = (w & 1) * 64;
  const int grow0 = CVTA ? n0 : m0;  // gload-side row base
  const int frow0 = CVTA ? m0 : n0;  // cvt-side row base
  const int frow = t >> 3, fcol = (t & 7) << 2;
  const size_t fbase = (size_t)(frow0 + frow) * K + fcol;
  const int o0 = w * 2048 + l * 16;
  const int o1 = o0 + 1024;
  const int r0 = o0 >> 6, c0 = o0 & 63;  // 64B per LDS row (32 shorts)
  const int r1 = o1 >> 6, c1 = o1 & 63;
  const char* Gp8 = (const char*)Gp;
  const size_t gb0 = ((size_t)(grow0 + r0) * K) * 2 + c0;
  const size_t gb1 = ((size_t)(grow0 + r1) * K) * 2 + c1;

  f32x4 acc[4][4];
#pragma unroll
  for (int i = 0; i < 4; ++i)
#pragma unroll
    for (int j = 0; j < 4; ++j) acc[i][j] = {0.f, 0.f, 0.f, 0.f};

  auto stageG = [&](int u) {  // sub-tile u -> Gs[u%6]
    char* gd = (char*)&Gs[u % 6][0];
    gload16(Gp8 + gb0 + (size_t)u * 64, gd + o0);
    gload16(Gp8 + gb1 + (size_t)u * 64, gd + o1);
  };
  auto loadF = [&](int u, f32x4* av) {
#pragma unroll
    for (int i = 0; i < 4; ++i)
      av[i] = *(const f32x4*)&Fp[fbase + (size_t)i * 32 * K + (size_t)u * 32];
  };
  auto writeF = [&](int u, const f32x4* av) {
#pragma unroll
    for (int i = 0; i < 4; ++i) {
      i32x2 pw = {cvtpk(av[i][0], av[i][1]), cvtpk(av[i][2], av[i][3])};
      *(i32x2*)&Cs[u % 4][(frow + i * 32) * 32 + fcol] = pw;
    }
  };
  auto mfsub = [&](int u) {
    const short* Asb = CVTA ? &Cs[u % 4][0] : &Gs[u % 6][0];
    const short* Bsb = CVTA ? &Gs[u % 6][0] : &Cs[u % 4][0];
    bf16x8 af[4], bfr[4];
#pragma unroll
    for (int mi = 0; mi < 4; ++mi)
      af[mi] = *(const bf16x8*)&Asb[(wr + mi * 16 + ln) * 32 + g * 8];
#pragma unroll
    for (int ni = 0; ni < 4; ++ni)
      bfr[ni] = *(const bf16x8*)&Bsb[(wc + ni * 16 + ln) * 32 + g * 8];
#pragma unroll
    for (int mi = 0; mi < 4; ++mi)
#pragma unroll
      for (int ni = 0; ni < 4; ++ni)
        acc[mi][ni] = mfma16(af[mi], bfr[ni], acc[mi][ni]);
  };

  // ---- prologue: F(0,1)->Cs; G(0..3) gloads (2 pairs ahead) ----
  {
    f32x4 a0[4], a1[4];
    loadF(0, a0);
    loadF(1, a1);
    __builtin_amdgcn_sched_barrier(0);
    stageG(0); stageG(1); stageG(2); stageG(3);
    writeF(0, a0);
    writeF(1, a1);
    wait_vm4_lgkm0();  // subs 0,1 landed; 2,3 in flight
    __builtin_amdgcn_sched_barrier(0);
    __builtin_amdgcn_s_barrier();
    __builtin_amdgcn_sched_barrier(0);
  }

  for (int p = 0; p < 16; ++p) {
    const int u0 = 2 * p, u1 = 2 * p + 1;
    f32x4 b0[4], b1[4];
    if (p < 15) {  // F reg-loads for pair p+1
      loadF(u0 + 2, b0);
      loadF(u1 + 2, b1);
    }
    __builtin_amdgcn_sched_barrier(0);
    if (p < 14) {  // G gloads for pair p+2
      stageG(u0 + 4);
      stageG(u1 + 4);
    }
    mfsub(u0);
    mfsub(u1);
    if (p < 15) {  // cvt+write F pair p+1
      writeF(u0 + 2, b0);
      writeF(u1 + 2, b1);
      if (p < 14)
        wait_vm4_lgkm0();  // pair p+1 landed; pair p+2 stays in flight
      else
        wait_vm0_lgkm0();
      __builtin_amdgcn_sched_barrier(0);
      __builtin_amdgcn_s_barrier();
      __builtin_amdgcn_sched_barrier(0);
    }
  }

  // C/D (16x16): col = lane&15, row = (lane>>4)*4 + reg
#pragma unroll
  for (int mi = 0; mi < 4; ++mi)
#pragma unroll
    for (int ni = 0; ni < 4; ++ni)
#pragma unroll
      for (int r = 0; r < 4; ++r) {
        int row = m0 + wr + mi * 16 + g * 4 + r;
        int col = n0 + wc + ni * 16 + ln;
        float v = (acc[mi][ni][r] + bias[col]) * scale;
        if constexpr (MODE == 0) {
          ((float*)outp)[(size_t)row * CE + col] = v;
        } else if constexpr (MODE == 1) {
          int b = row >> 11, s = row & 2047, h = col >> 6, d = col & 63;
          ((short*)outp)[(((size_t)(b * CH + h)) * CS + s) * CDH + d] =
              f2bf(v);
        } else {
          int b = row >> 11, s = row & 2047, h = col >> 6, d = col & 63;
          int sp = (s & ~12) | ((s & 4) << 1) | ((s & 8) >> 1);  // swap b2,b3
          ((short*)outp)[(((size_t)(b * CH + h)) * CDH + d) * CS + sp] =
              f2bf(v);
        }
      }
}

// ---------------- Flash attention: 8-wave kv-split, fixed-max ---------------
// 512 threads: waves 0-3 do kv tiles 0..15, waves 4-7 do 16..31, same 256
// q-rows. Fixed-max softmax (exp2(s-8), no max tracking) makes the partial
// accO/accS sums exactly additive -> LDS combine epilogue. 80KB LDS ->
// 2 blocks/CU = 16 waves/CU = 4 waves/SIMD (vs 2 before; attn was
// issue-limited at 2). Per half: K 3-ring (staged t+2), V 2-ring (staged
// t+1, issued before K so vmcnt(2) leaves only K in flight).
struct AttnCtx {
  int lo, hi, swl;
};

DEVI void qk_half(const char* Kc, const bf16x8 qfh[4], f32x16 sc[2],
                  const AttnCtx& c) {
#pragma unroll
  for (int mb = 0; mb < 2; ++mb) {
    const char* krp = Kc + (mb * 32 + c.lo) * 128;
#pragma unroll
    for (int ks = 0; ks < 4; ++ks) {
      bf16x8 kf = *(const bf16x8*)(krp + ((ks * 32 + c.hi * 16) ^ c.swl));
      sc[mb] = mfma32(kf, qfh[ks], sc[mb]);
    }
  }
}

DEVI void smpv_half(f32x16 sc[2], const char* Vc, f32x16 accO[2],
                    f32x16& accS, const bf16x8& ones, const AttnCtx& c) {
  // p = exp2(s - 8), fixed max: no tracking, no rescale (exact softmax)
#pragma unroll
  for (int mb = 0; mb < 2; ++mb)
#pragma unroll
    for (int i = 0; i < 16; ++i) sc[mb][i] = exp2v(sc[mb][i] - 8.f);

  bf16x8 pf[4];
#pragma unroll
  for (int kst = 0; kst < 4; ++kst) {
    const int mb = kst >> 1, o8 = (kst & 1) * 8;
    i32x4 pw = {cvtpk(sc[mb][o8 + 0], sc[mb][o8 + 1]),
                cvtpk(sc[mb][o8 + 2], sc[mb][o8 + 3]),
                cvtpk(sc[mb][o8 + 4], sc[mb][o8 + 5]),
                cvtpk(sc[mb][o8 + 6], sc[mb][o8 + 7])};
    pf[kst] = __builtin_bit_cast(bf16x8, pw);
  }
#pragma unroll
  for (int nb = 0; nb < 2; ++nb) {
    const char* vrp = Vc + (nb * 32 + c.lo) * 128;
#pragma unroll
    for (int kst = 0; kst < 4; ++kst) {
      bf16x8 vf = *(const bf16x8*)(vrp + ((kst * 32 + c.hi * 16) ^ c.swl));
      accO[nb] = mfma32(pf[kst], vf, accO[nb]);
    }
  }
#pragma unroll
  for (int kst = 0; kst < 4; ++kst) accS = mfma32(pf[kst], ones, accS);
}

__global__ __launch_bounds__(512, 4) void attn_fwd(
    const short* __restrict__ qp, const short* __restrict__ kp,
    const short* __restrict__ vtp, short* __restrict__ outp) {
  __shared__ short Ks[2][3][64 * 64];  // [half][ring]  48KB
  __shared__ short Vs[2][2][64 * 64];  // [half][ring]  32KB
  const int tid = threadIdx.x;
  const int w = tid >> 6;      // 0..7
  const int half = w >> 2;     // kv half (0: tiles 0..15, 1: 16..31)
  const int wl = w & 3;        // wave within half
  const int l = tid & 63;
  const int lo = l & 31, hi = l >> 5;
  const int lin = blockIdx.x;
  const int wg = (lin & 7) * 64 + (lin >> 3);
  const int qb = wg & 7, bh = wg >> 3;
  const int b = bh >> 4, h = bh & 15;
  const AttnCtx ctx = {lo, hi, (lo & 7) << 4};

  const short* qbase = qp + ((size_t)bh * CS + qb * 256 + wl * 64) * CDH;
  bf16x8 qf[2][4];
#pragma unroll
  for (int qk = 0; qk < 2; ++qk)
#pragma unroll
    for (int ks = 0; ks < 4; ++ks)
      qf[qk][ks] =
          *(const bf16x8*)&qbase[(qk * 32 + lo) * CDH + ks * 16 + hi * 8];

  // staging: 256 threads per half; pre-XOR-swizzled source chunks
  const int t8 = tid & 255;
  const int srow = t8 >> 3;
  const int soff = ((t8 & 7) * 16) ^ ((srow & 7) << 4);
  const char* kb =
      (const char*)kp + ((size_t)bh * CS + half * 1024) * 128;
  const char* vb = (const char*)vtp + (size_t)bh * CDH * (CS * 2);
  const char* ksrc0 = kb + (size_t)srow * 128 + soff;
  const char* ksrc1 = kb + (size_t)(srow + 32) * 128 + soff;
  const char* vsrc0 = vb + (size_t)srow * (CS * 2) + half * 2048 + soff;
  const char* vsrc1 = vb + (size_t)(srow + 32) * (CS * 2) + half * 2048 + soff;

  const bf16x8 ones = {0x3F80, 0x3F80, 0x3F80, 0x3F80,
                       0x3F80, 0x3F80, 0x3F80, 0x3F80};

  f32x16 accO[2][2] = {};  // [stream][nb]
  f32x16 accS[2] = {};     // [stream]

  // prologue: K[0], V[0], K[1]; vmcnt(2) leaves K[1] in flight
  gload16(ksrc0, (char*)&Ks[half][0][0] + t8 * 16);
  gload16(ksrc1, (char*)&Ks[half][0][0] + t8 * 16 + 4096);
  gload16(vsrc0, (char*)&Vs[half][0][0] + t8 * 16);
  gload16(vsrc1, (char*)&Vs[half][0][0] + t8 * 16 + 4096);
  gload16(ksrc0 + 8192, (char*)&Ks[half][1][0] + t8 * 16);
  gload16(ksrc1 + 8192, (char*)&Ks[half][1][0] + t8 * 16 + 4096);
  __builtin_amdgcn_sched_barrier(0);
  wait_vm2_lgkm0();
  __builtin_amdgcn_sched_barrier(0);
  __builtin_amdgcn_s_barrier();
  __builtin_amdgcn_sched_barrier(0);

  int krd = 0;  // K read slot (t % 3)
  for (int t = 0; t < 16; ++t) {
    const int vrd = t & 1;
    // issue V[t+1] first (older), then K[t+2] (newest 2 stay in flight)
    if (t < 15) {
      size_t vo = (size_t)(t + 1) * 128;
      char* vd = (char*)&Vs[half][vrd ^ 1][0] + t8 * 16;
      gload16(vsrc0 + vo, vd);
      gload16(vsrc1 + vo, vd + 4096);
    }
    if (t < 14) {
      int kws = krd + 2;
      if (kws >= 3) kws -= 3;
      size_t ko = (size_t)(t + 2) * 8192;
      char* kd = (char*)&Ks[half][kws][0] + t8 * 16;
      gload16(ksrc0 + ko, kd);
      gload16(ksrc1 + ko, kd + 4096);
    }

    const char* Kc = (const char*)&Ks[half][krd][0];
    const char* Vc = (const char*)&Vs[half][vrd][0];

    f32x16 sc[2] = {};
    qk_half(Kc, qf[0], sc, ctx);                      // stream A: QK(t)
    smpv_half(sc, Vc, accO[0], accS[0], ones, ctx);   // stream A: SM+PV(t)
    f32x16 sd[2] = {};
    qk_half(Kc, qf[1], sd, ctx);                      // stream B: QK(t)
    smpv_half(sd, Vc, accO[1], accS[1], ones, ctx);   // stream B: SM+PV(t)

    if (t < 15) {  // counted-vmcnt barrier: K[t+2] stays in flight
      __builtin_amdgcn_sched_barrier(0);
      if (t < 14)
        wait_vm2_lgkm0();
      else
        wait_vm0_lgkm0();  // t==14: drain V[15] for the last tile
      __builtin_amdgcn_sched_barrier(0);
      __builtin_amdgcn_s_barrier();
      __builtin_amdgcn_sched_barrier(0);
    }
    krd = (krd == 2) ? 0 : krd + 1;
  }

  // ---- combine epilogue: upper half writes partials, lower half adds ----
  __syncthreads();
  float* cb = (float*)&Ks[0][0][0];  // 48KB scratch ([wl][3][16][64] floats)
#pragma unroll
  for (int st = 0; st < 2; ++st) {
    if (half == 1) {
      float* bp = cb + wl * 3072;
#pragma unroll
      for (int i = 0; i < 16; ++i) {
        bp[i * 64 + l]        = accO[st][0][i];
        bp[1024 + i * 64 + l] = accO[st][1][i];
        bp[2048 + i * 64 + l] = accS[st][i];
      }
    }
    __syncthreads();
    if (half == 0) {
      const float* bp = cb + wl * 3072;
#pragma unroll
      for (int i = 0; i < 16; ++i) {
        accO[st][0][i] += bp[i * 64 + l];
        accO[st][1][i] += bp[1024 + i * 64 + l];
        accS[st][i]    += bp[2048 + i * 64 + l];
      }
    }
    __syncthreads();
  }
  if (half == 1) return;

  // normalize (per-reg rcp of combined row-sum) and store
#pragma unroll
  for (int qk = 0; qk < 2; ++qk) {
    f32x16 iv;
#pragma unroll
    for (int r = 0; r < 16; ++r) iv[r] = rcpv(accS[qk][r]);
#pragma unroll
    for (int nb = 0; nb < 2; ++nb) {
      f32x16 val = accO[qk][nb] * iv;
#pragma unroll
      for (int r = 0; r < 16; ++r) {
        int sg = qb * 256 + wl * 64 + qk * 32 + (r & 3) + 8 * (r >> 2) + 4 * hi;
        outp[((size_t)(b * CS + sg)) * CE + h * CDH + nb * 32 + lo] =
            f2bf(val[r]);
      }
    }
  }
}

extern "C" void kernel_launch(void* const* d_in, const int* in_sizes, int n_in,
                              void* d_out, int out_size, void* d_ws,
                              size_t ws_size, hipStream_t stream) {
  const float* queries = (const float*)d_in[0];
  const float* keys    = (const float*)d_in[1];
  const float* values  = (const float*)d_in[2];
  const float* Wq = (const float*)d_in[3];
  const float* bq = (const float*)d_in[4];
  const float* Wk = (const float*)d_in[5];
  const float* bk = (const float*)d_in[6];
  const float* Wv = (const float*)d_in[7];
  const float* bv = (const float*)d_in[8];
  const float* Wo = (const float*)d_in[9];
  const float* bo = (const float*)d_in[10];

  const size_t NELT = (size_t)CB * CS * CE;  // 8388608
  short* R1  = (short*)d_ws;        // attn output (bf16 [B,S,E])
  short* qp  = R1 + NELT;
  short* kp  = qp + NELT;
  short* vtp = kp + NELT;
  // W16 scratch lives in d_out (dead until the final GEMM overwrites it)
  short* w16q = (short*)d_out;
  short* w16k = w16q + (size_t)CE * CE;
  short* w16v = w16k + (size_t)CE * CE;

  dim3 blk(256);
  const float qscale = 0.18033688011112042f;  // log2(e) / sqrt(DH)

  cvtW3<<<dim3(512, 3), blk, 0, stream>>>(Wq, Wk, Wv, w16q, w16k, w16v);
  gemm2<1, true><<<512, blk, 0, stream>>>(w16q, queries, bq, qp, qscale);
  gemm2<1, true><<<512, blk, 0, stream>>>(w16k, keys, bk, kp, 1.0f);
  gemm2<2, true><<<512, blk, 0, stream>>>(w16v, values, bv, vtp, 1.0f);
  attn_fwd<<<512, dim3(512), 0, stream>>>(qp, kp, vtp, R1);
  gemm2<0, false><<<512, blk, 0, stream>>>(R1, Wo, bo, (float*)d_out, 1.0f);
}

// Round 11
// 198.955 us; speedup vs baseline: 4.2446x; 4.2446x over previous
//
#include <hip/hip_runtime.h>
#include <stdint.h>

typedef __attribute__((ext_vector_type(4))) float f32x4;
typedef __attribute__((ext_vector_type(8))) float f32x8;
typedef __attribute__((ext_vector_type(16))) float f32x16;
typedef __attribute__((ext_vector_type(8))) short bf16x8;
typedef __attribute__((ext_vector_type(4))) int i32x4;
typedef __attribute__((ext_vector_type(2))) int i32x2;

#define DEVI static __device__ __forceinline__

constexpr int CB  = 4;     // batch
constexpr int CS  = 2048;  // seq
constexpr int CH  = 16;    // heads
constexpr int CDH = 64;    // head dim
constexpr int CE  = 1024;  // embed

DEVI short f2bf(float x) {  // RNE float->bf16 (epilogue use)
  unsigned u = __float_as_uint(x);
  u += 0x7fffu + ((u >> 16) & 1u);
  return (short)(u >> 16);
}

DEVI int cvtpk(float lo, float hi) {  // packed f32x2 -> bf16x2 (RNE, 1 inst)
  int r;
  asm("v_cvt_pk_bf16_f32 %0, %1, %2" : "=v"(r) : "v"(lo), "v"(hi));
  return r;
}

DEVI float exp2v(float x) {  // raw v_exp_f32 (2^x)
  float r;
  asm("v_exp_f32 %0, %1" : "=v"(r) : "v"(x));
  return r;
}

DEVI float rcpv(float x) {  // v_rcp_f32 (~1 ulp)
  float r;
  asm("v_rcp_f32 %0, %1" : "=v"(r) : "v"(x));
  return r;
}

DEVI void gload16(const void* g, void* l) {
  __builtin_amdgcn_global_load_lds(
      (const __attribute__((address_space(1))) void*)g,
      (__attribute__((address_space(3))) void*)l, 16, 0, 0);
}

DEVI f32x4 mfma16(bf16x8 a, bf16x8 b, f32x4 c) {
  return __builtin_amdgcn_mfma_f32_16x16x32_bf16(a, b, c, 0, 0, 0);
}
DEVI f32x16 mfma32(bf16x8 a, bf16x8 b, f32x16 c) {
  return __builtin_amdgcn_mfma_f32_32x32x16_bf16(a, b, c, 0, 0, 0);
}

DEVI float rsum16(f32x16 v) {
  f32x8 a = __builtin_shufflevector(v, v, 0, 1, 2, 3, 4, 5, 6, 7);
  f32x8 b = __builtin_shufflevector(v, v, 8, 9, 10, 11, 12, 13, 14, 15);
  a = a + b;
  f32x4 c = __builtin_shufflevector(a, a, 0, 1, 2, 3);
  f32x4 d = __builtin_shufflevector(a, a, 4, 5, 6, 7);
  c = c + d;
  return (c[0] + c[1]) + (c[2] + c[3]);
}

DEVI void wait_vm4_lgkm0() {
  asm volatile("s_waitcnt vmcnt(4) lgkmcnt(0)" ::: "memory");
}
DEVI void wait_vm2_lgkm0() {
  asm volatile("s_waitcnt vmcnt(2) lgkmcnt(0)" ::: "memory");
}
DEVI void wait_vm0_lgkm0() {
  asm volatile("s_waitcnt vmcnt(0) lgkmcnt(0)" ::: "memory");
}

// ---------------- W fp32 -> bf16 (once; reused by 3 projections) ------------

__global__ __launch_bounds__(256) void cvtW3(
    const float* __restrict__ w0, const float* __restrict__ w1,
    const float* __restrict__ w2, short* __restrict__ o0,
    short* __restrict__ o1, short* __restrict__ o2) {
  const float* in = blockIdx.y == 0 ? w0 : (blockIdx.y == 1 ? w1 : w2);
  short* out = blockIdx.y == 0 ? o0 : (blockIdx.y == 1 ? o1 : o2);
  size_t o = ((size_t)blockIdx.x * 256 + threadIdx.x) * 8;
  f32x4 a = *(const f32x4*)&in[o];
  f32x4 b = *(const f32x4*)&in[o + 4];
  i32x4 p = {cvtpk(a[0], a[1]), cvtpk(a[2], a[3]),
             cvtpk(b[0], b[1]), cvtpk(b[2], b[3])};
  *(i32x4*)&out[o] = p;
}

// ---------------- Pipelined GEMM: C = A * W^T + bias (round 8, kept) --------
template<int MODE, bool CVTA>
__global__ __launch_bounds__(256) void gemm2(
    const short* __restrict__ Gp, const float* __restrict__ Fp,
    const float* __restrict__ bias, void* __restrict__ outp, float scale) {
  constexpr int K = CE;
  __shared__ short Gs[6][128 * 32];  // 48KB
  __shared__ short Cs[4][128 * 32];  // 32KB
  const int t  = threadIdx.x;
  const int l  = t & 63;
  const int w  = t >> 6;
  const int g  = l >> 4;
  const int ln = l & 15;
  const int lin = blockIdx.x;
  const int wg = (lin & 7) * 64 + (lin >> 3);
  const int n0 = (wg & 7) * 128;
  const int m0 = (wg >> 3) * 128;
  const int wr = (w >> 1) * 64;
  const int wc = (w & 1) * 64;
  const int grow0 = CVTA ? n0 : m0;  // gload-side row base
  const int frow0 = CVTA ? m0 : n0;  // cvt-side row base
  const int frow = t >> 3, fcol = (t & 7) << 2;
  const size_t fbase = (size_t)(frow0 + frow) * K + fcol;
  const int o0 = w * 2048 + l * 16;
  const int o1 = o0 + 1024;
  const int r0 = o0 >> 6, c0 = o0 & 63;  // 64B per LDS row (32 shorts)
  const int r1 = o1 >> 6, c1 = o1 & 63;
  const char* Gp8 = (const char*)Gp;
  const size_t gb0 = ((size_t)(grow0 + r0) * K) * 2 + c0;
  const size_t gb1 = ((size_t)(grow0 + r1) * K) * 2 + c1;

  f32x4 acc[4][4];
#pragma unroll
  for (int i = 0; i < 4; ++i)
#pragma unroll
    for (int j = 0; j < 4; ++j) acc[i][j] = {0.f, 0.f, 0.f, 0.f};

  auto stageG = [&](int u) {  // sub-tile u -> Gs[u%6]
    char* gd = (char*)&Gs[u % 6][0];
    gload16(Gp8 + gb0 + (size_t)u * 64, gd + o0);
    gload16(Gp8 + gb1 + (size_t)u * 64, gd + o1);
  };
  auto loadF = [&](int u, f32x4* av) {
#pragma unroll
    for (int i = 0; i < 4; ++i)
      av[i] = *(const f32x4*)&Fp[fbase + (size_t)i * 32 * K + (size_t)u * 32];
  };
  auto writeF = [&](int u, const f32x4* av) {
#pragma unroll
    for (int i = 0; i < 4; ++i) {
      i32x2 pw = {cvtpk(av[i][0], av[i][1]), cvtpk(av[i][2], av[i][3])};
      *(i32x2*)&Cs[u % 4][(frow + i * 32) * 32 + fcol] = pw;
    }
  };
  auto mfsub = [&](int u) {
    const short* Asb = CVTA ? &Cs[u % 4][0] : &Gs[u % 6][0];
    const short* Bsb = CVTA ? &Gs[u % 6][0] : &Cs[u % 4][0];
    bf16x8 af[4], bfr[4];
#pragma unroll
    for (int mi = 0; mi < 4; ++mi)
      af[mi] = *(const bf16x8*)&Asb[(wr + mi * 16 + ln) * 32 + g * 8];
#pragma unroll
    for (int ni = 0; ni < 4; ++ni)
      bfr[ni] = *(const bf16x8*)&Bsb[(wc + ni * 16 + ln) * 32 + g * 8];
#pragma unroll
    for (int mi = 0; mi < 4; ++mi)
#pragma unroll
      for (int ni = 0; ni < 4; ++ni)
        acc[mi][ni] = mfma16(af[mi], bfr[ni], acc[mi][ni]);
  };

  // ---- prologue: F(0,1)->Cs; G(0..3) gloads (2 pairs ahead) ----
  {
    f32x4 a0[4], a1[4];
    loadF(0, a0);
    loadF(1, a1);
    __builtin_amdgcn_sched_barrier(0);
    stageG(0); stageG(1); stageG(2); stageG(3);
    writeF(0, a0);
    writeF(1, a1);
    wait_vm4_lgkm0();  // subs 0,1 landed; 2,3 in flight
    __builtin_amdgcn_sched_barrier(0);
    __builtin_amdgcn_s_barrier();
    __builtin_amdgcn_sched_barrier(0);
  }

  for (int p = 0; p < 16; ++p) {
    const int u0 = 2 * p, u1 = 2 * p + 1;
    f32x4 b0[4], b1[4];
    if (p < 15) {  // F reg-loads for pair p+1
      loadF(u0 + 2, b0);
      loadF(u1 + 2, b1);
    }
    __builtin_amdgcn_sched_barrier(0);
    if (p < 14) {  // G gloads for pair p+2
      stageG(u0 + 4);
      stageG(u1 + 4);
    }
    mfsub(u0);
    mfsub(u1);
    if (p < 15) {  // cvt+write F pair p+1
      writeF(u0 + 2, b0);
      writeF(u1 + 2, b1);
      if (p < 14)
        wait_vm4_lgkm0();  // pair p+1 landed; pair p+2 stays in flight
      else
        wait_vm0_lgkm0();
      __builtin_amdgcn_sched_barrier(0);
      __builtin_amdgcn_s_barrier();
      __builtin_amdgcn_sched_barrier(0);
    }
  }

  // C/D (16x16): col = lane&15, row = (lane>>4)*4 + reg
#pragma unroll
  for (int mi = 0; mi < 4; ++mi)
#pragma unroll
    for (int ni = 0; ni < 4; ++ni)
#pragma unroll
      for (int r = 0; r < 4; ++r) {
        int row = m0 + wr + mi * 16 + g * 4 + r;
        int col = n0 + wc + ni * 16 + ln;
        float v = (acc[mi][ni][r] + bias[col]) * scale;
        if constexpr (MODE == 0) {
          ((float*)outp)[(size_t)row * CE + col] = v;
        } else if constexpr (MODE == 1) {
          int b = row >> 11, s = row & 2047, h = col >> 6, d = col & 63;
          ((short*)outp)[(((size_t)(b * CH + h)) * CS + s) * CDH + d] =
              f2bf(v);
        } else {
          int b = row >> 11, s = row & 2047, h = col >> 6, d = col & 63;
          int sp = (s & ~12) | ((s & 4) << 1) | ((s & 8) >> 1);  // swap b2,b3
          ((short*)outp)[(((size_t)(b * CH + h)) * CDH + d) * CS + sp] =
              f2bf(v);
        }
      }
}

// ---------------- Flash attention: 8-wave kv-split, fixed-max ---------------
// 512 threads: waves 0-3 do kv tiles 0..15, waves 4-7 do 16..31, same 256
// q-rows. Fixed-max softmax (exp2(s-8)) makes partials exactly additive ->
// LDS combine epilogue. 80KB LDS -> 2 blocks/CU = 16 waves/CU = 4 waves/SIMD.
// __launch_bounds__(512,2): CUDA-style min-2-blocks/CU -> VGPR cap 128
// (r10's (512,4) capped at 64 and spilled all accumulators to scratch).
// Row-sums via VALU (rsum16 + shfl_xor32 into 1 scalar/stream) instead of
// ones-MFMA f32x16 accS: saves 30 VGPRs to fit the 128 cap.
struct AttnCtx {
  int lo, hi, swl;
};

DEVI void qk_half(const char* Kc, const bf16x8 qfh[4], f32x16 sc[2],
                  const AttnCtx& c) {
#pragma unroll
  for (int mb = 0; mb < 2; ++mb) {
    const char* krp = Kc + (mb * 32 + c.lo) * 128;
#pragma unroll
    for (int ks = 0; ks < 4; ++ks) {
      bf16x8 kf = *(const bf16x8*)(krp + ((ks * 32 + c.hi * 16) ^ c.swl));
      sc[mb] = mfma32(kf, qfh[ks], sc[mb]);
    }
  }
}

DEVI void smpv_half(f32x16 sc[2], const char* Vc, f32x16 accO[2],
                    float& accS, const AttnCtx& c) {
  // p = exp2(s - 8), fixed max: no tracking, no rescale (exact softmax)
#pragma unroll
  for (int mb = 0; mb < 2; ++mb)
#pragma unroll
    for (int i = 0; i < 16; ++i) sc[mb][i] = exp2v(sc[mb][i] - 8.f);

  // row-sum for this lane's q (=lo): lane holds all 32 kv of its column
  float ls = rsum16(sc[0] + sc[1]);
  ls += __shfl_xor(ls, 32, 64);
  accS += ls;

  bf16x8 pf[4];
#pragma unroll
  for (int kst = 0; kst < 4; ++kst) {
    const int mb = kst >> 1, o8 = (kst & 1) * 8;
    i32x4 pw = {cvtpk(sc[mb][o8 + 0], sc[mb][o8 + 1]),
                cvtpk(sc[mb][o8 + 2], sc[mb][o8 + 3]),
                cvtpk(sc[mb][o8 + 4], sc[mb][o8 + 5]),
                cvtpk(sc[mb][o8 + 6], sc[mb][o8 + 7])};
    pf[kst] = __builtin_bit_cast(bf16x8, pw);
  }
#pragma unroll
  for (int nb = 0; nb < 2; ++nb) {
    const char* vrp = Vc + (nb * 32 + c.lo) * 128;
#pragma unroll
    for (int kst = 0; kst < 4; ++kst) {
      bf16x8 vf = *(const bf16x8*)(vrp + ((kst * 32 + c.hi * 16) ^ c.swl));
      accO[nb] = mfma32(pf[kst], vf, accO[nb]);
    }
  }
}

__global__ __launch_bounds__(512, 2) void attn_fwd(
    const short* __restrict__ qp, const short* __restrict__ kp,
    const short* __restrict__ vtp, short* __restrict__ outp) {
  __shared__ short Ks[2][3][64 * 64];  // [half][ring]  48KB
  __shared__ short Vs[2][2][64 * 64];  // [half][ring]  32KB
  const int tid = threadIdx.x;
  const int w = tid >> 6;      // 0..7
  const int half = w >> 2;     // kv half (0: tiles 0..15, 1: 16..31)
  const int wl = w & 3;        // wave within half
  const int l = tid & 63;
  const int lo = l & 31, hi = l >> 5;
  const int lin = blockIdx.x;
  const int wg = (lin & 7) * 64 + (lin >> 3);
  const int qb = wg & 7, bh = wg >> 3;
  const int b = bh >> 4, h = bh & 15;
  const AttnCtx ctx = {lo, hi, (lo & 7) << 4};

  const short* qbase = qp + ((size_t)bh * CS + qb * 256 + wl * 64) * CDH;
  bf16x8 qf[2][4];
#pragma unroll
  for (int qk = 0; qk < 2; ++qk)
#pragma unroll
    for (int ks = 0; ks < 4; ++ks)
      qf[qk][ks] =
          *(const bf16x8*)&qbase[(qk * 32 + lo) * CDH + ks * 16 + hi * 8];

  // staging: 256 threads per half; pre-XOR-swizzled source chunks
  const int t8 = tid & 255;
  const int srow = t8 >> 3;
  const int soff = ((t8 & 7) * 16) ^ ((srow & 7) << 4);
  const char* kb =
      (const char*)kp + ((size_t)bh * CS + half * 1024) * 128;
  const char* vb = (const char*)vtp + (size_t)bh * CDH * (CS * 2);
  const char* ksrc0 = kb + (size_t)srow * 128 + soff;
  const char* ksrc1 = kb + (size_t)(srow + 32) * 128 + soff;
  const char* vsrc0 = vb + (size_t)srow * (CS * 2) + half * 2048 + soff;
  const char* vsrc1 = vb + (size_t)(srow + 32) * (CS * 2) + half * 2048 + soff;

  f32x16 accO[2][2] = {};  // [stream][nb]
  float accS[2] = {0.f, 0.f};

  // prologue: K[0], V[0], K[1]; vmcnt(2) leaves K[1] in flight
  gload16(ksrc0, (char*)&Ks[half][0][0] + t8 * 16);
  gload16(ksrc1, (char*)&Ks[half][0][0] + t8 * 16 + 4096);
  gload16(vsrc0, (char*)&Vs[half][0][0] + t8 * 16);
  gload16(vsrc1, (char*)&Vs[half][0][0] + t8 * 16 + 4096);
  gload16(ksrc0 + 8192, (char*)&Ks[half][1][0] + t8 * 16);
  gload16(ksrc1 + 8192, (char*)&Ks[half][1][0] + t8 * 16 + 4096);
  __builtin_amdgcn_sched_barrier(0);
  wait_vm2_lgkm0();
  __builtin_amdgcn_sched_barrier(0);
  __builtin_amdgcn_s_barrier();
  __builtin_amdgcn_sched_barrier(0);

  int krd = 0;  // K read slot (t % 3)
  for (int t = 0; t < 16; ++t) {
    const int vrd = t & 1;
    // issue V[t+1] first (older), then K[t+2] (newest 2 stay in flight)
    if (t < 15) {
      size_t vo = (size_t)(t + 1) * 128;
      char* vd = (char*)&Vs[half][vrd ^ 1][0] + t8 * 16;
      gload16(vsrc0 + vo, vd);
      gload16(vsrc1 + vo, vd + 4096);
    }
    if (t < 14) {
      int kws = krd + 2;
      if (kws >= 3) kws -= 3;
      size_t ko = (size_t)(t + 2) * 8192;
      char* kd = (char*)&Ks[half][kws][0] + t8 * 16;
      gload16(ksrc0 + ko, kd);
      gload16(ksrc1 + ko, kd + 4096);
    }

    const char* Kc = (const char*)&Ks[half][krd][0];
    const char* Vc = (const char*)&Vs[half][vrd][0];

    f32x16 sc[2] = {};
    qk_half(Kc, qf[0], sc, ctx);               // stream A: QK(t)
    smpv_half(sc, Vc, accO[0], accS[0], ctx);  // stream A: SM+PV(t)
    f32x16 sd[2] = {};
    qk_half(Kc, qf[1], sd, ctx);               // stream B: QK(t)
    smpv_half(sd, Vc, accO[1], accS[1], ctx);  // stream B: SM+PV(t)

    if (t < 15) {  // counted-vmcnt barrier: K[t+2] stays in flight
      __builtin_amdgcn_sched_barrier(0);
      if (t < 14)
        wait_vm2_lgkm0();
      else
        wait_vm0_lgkm0();  // t==14: drain V[15] for the last tile
      __builtin_amdgcn_sched_barrier(0);
      __builtin_amdgcn_s_barrier();
      __builtin_amdgcn_sched_barrier(0);
    }
    krd = (krd == 2) ? 0 : krd + 1;
  }

  // ---- combine epilogue: upper half writes partials, lower half adds ----
  __syncthreads();
  float* cb = (float*)&Ks[0][0][0];  // scratch: [wl][2112 floats/stream]
#pragma unroll
  for (int st = 0; st < 2; ++st) {
    if (half == 1) {
      float* bp = cb + wl * 2112;
#pragma unroll
      for (int i = 0; i < 16; ++i) {
        bp[i * 64 + l]        = accO[st][0][i];
        bp[1024 + i * 64 + l] = accO[st][1][i];
      }
      bp[2048 + l] = accS[st];
    }
    __syncthreads();
    if (half == 0) {
      const float* bp = cb + wl * 2112;
#pragma unroll
      for (int i = 0; i < 16; ++i) {
        accO[st][0][i] += bp[i * 64 + l];
        accO[st][1][i] += bp[1024 + i * 64 + l];
      }
      accS[st] += bp[2048 + l];
    }
    __syncthreads();
  }
  if (half == 1) return;

  // normalize: inv lives at lane q=lo; distribute to accO rows via shfl
#pragma unroll
  for (int qk = 0; qk < 2; ++qk) {
    float inv = rcpv(accS[qk]);
    f32x16 iv;
#pragma unroll
    for (int r = 0; r < 16; ++r)
      iv[r] = __shfl(inv, (r & 3) + 8 * (r >> 2) + 4 * hi, 64);
#pragma unroll
    for (int nb = 0; nb < 2; ++nb) {
      f32x16 val = accO[qk][nb] * iv;
#pragma unroll
      for (int r = 0; r < 16; ++r) {
        int sg = qb * 256 + wl * 64 + qk * 32 + (r & 3) + 8 * (r >> 2) + 4 * hi;
        outp[((size_t)(b * CS + sg)) * CE + h * CDH + nb * 32 + lo] =
            f2bf(val[r]);
      }
    }
  }
}

extern "C" void kernel_launch(void* const* d_in, const int* in_sizes, int n_in,
                              void* d_out, int out_size, void* d_ws,
                              size_t ws_size, hipStream_t stream) {
  const float* queries = (const float*)d_in[0];
  const float* keys    = (const float*)d_in[1];
  const float* values  = (const float*)d_in[2];
  const float* Wq = (const float*)d_in[3];
  const float* bq = (const float*)d_in[4];
  const float* Wk = (const float*)d_in[5];
  const float* bk = (const float*)d_in[6];
  const float* Wv = (const float*)d_in[7];
  const float* bv = (const float*)d_in[8];
  const float* Wo = (const float*)d_in[9];
  const float* bo = (const float*)d_in[10];

  const size_t NELT = (size_t)CB * CS * CE;  // 8388608
  short* R1  = (short*)d_ws;        // attn output (bf16 [B,S,E])
  short* qp  = R1 + NELT;
  short* kp  = qp + NELT;
  short* vtp = kp + NELT;
  // W16 scratch lives in d_out (dead until the final GEMM overwrites it)
  short* w16q = (short*)d_out;
  short* w16k = w16q + (size_t)CE * CE;
  short* w16v = w16k + (size_t)CE * CE;

  dim3 blk(256);
  const float qscale = 0.18033688011112042f;  // log2(e) / sqrt(DH)

  cvtW3<<<dim3(512, 3), blk, 0, stream>>>(Wq, Wk, Wv, w16q, w16k, w16v);
  gemm2<1, true><<<512, blk, 0, stream>>>(w16q, queries, bq, qp, qscale);
  gemm2<1, true><<<512, blk, 0, stream>>>(w16k, keys, bk, kp, 1.0f);
  gemm2<2, true><<<512, blk, 0, stream>>>(w16v, values, bv, vtp, 1.0f);
  attn_fwd<<<512, dim3(512), 0, stream>>>(qp, kp, vtp, R1);
  gemm2<0, false><<<512, blk, 0, stream>>>(R1, Wo, bo, (float*)d_out, 1.0f);
}